// Round 20
// baseline (186.876 us; speedup 1.0000x reference)
//
#include <hip/hip_runtime.h>
#include <hip/hip_bf16.h>
#include <math.h>
#include <stdint.h>

// Problem constants
constexpr int Bn = 4, Tn = 1024, Cn = 1024, Hn = 16;
constexpr int BT = Bn * Tn;                 // 4096
constexpr long long BTC = (long long)BT * Cn;  // 4M elements
constexpr int CL = 64;                      // chunk length
constexpr int NC = Tn / CL;                 // 16 chunks

typedef __bf16 bf16x8_t __attribute__((ext_vector_type(8)));
typedef float f32x4_t __attribute__((ext_vector_type(4)));
typedef unsigned short us8_t __attribute__((ext_vector_type(8)));

__device__ __forceinline__ unsigned short f2bf_bits(float v) {
    __hip_bfloat16 h = __float2bfloat16(v);
    return *reinterpret_cast<unsigned short*>(&h);
}
__device__ __forceinline__ float bfbits2f(unsigned short u) {
    unsigned int x = (unsigned int)u << 16;
    return __uint_as_float(x);
}

// Direct global->LDS 16B/lane (wave-uniform LDS base + lane*16). CK-style casts.
__device__ __forceinline__ void gload16(const void* g, void* l) {
    auto const* gp = reinterpret_cast<const unsigned int __attribute__((address_space(1)))*>(
        reinterpret_cast<uintptr_t>(g));
    auto* lp = reinterpret_cast<unsigned int __attribute__((address_space(3)))*>(
        reinterpret_cast<uintptr_t>(l));
    __builtin_amdgcn_global_load_lds(gp, lp, 16, 0, 0);
}

// ---------------------------------------------------------------------------
// Transpose + convert, ALL 8 weights in one dispatch (z selects matrix).
// ---------------------------------------------------------------------------
__global__ __launch_bounds__(256) void transp8(const float* __restrict__ W0,
                                               const float* __restrict__ W1,
                                               const float* __restrict__ W2,
                                               const float* __restrict__ W3,
                                               const float* __restrict__ W4,
                                               const float* __restrict__ W5,
                                               const float* __restrict__ W6,
                                               const float* __restrict__ W7,
                                               __hip_bfloat16* __restrict__ T0,
                                               __hip_bfloat16* __restrict__ T1,
                                               __hip_bfloat16* __restrict__ T2,
                                               __hip_bfloat16* __restrict__ T3,
                                               __hip_bfloat16* __restrict__ T4,
                                               __hip_bfloat16* __restrict__ T5,
                                               __hip_bfloat16* __restrict__ T6,
                                               __hip_bfloat16* __restrict__ T7) {
    int z = blockIdx.z;
    const float* W;
    __hip_bfloat16* Wt;
    int R, Cc;
    if (z < 5) {
        W = (z == 0) ? W0 : (z == 1) ? W1 : (z == 2) ? W2 : (z == 3) ? W3 : W4;
        Wt = (z == 0) ? T0 : (z == 1) ? T1 : (z == 2) ? T2 : (z == 3) ? T3 : T4;
        R = Cn; Cc = Cn;
    } else if (z == 5) {
        if (blockIdx.x >= 5) return;       // Cc=160 -> 5 col-tiles
        W = W5; Wt = T5; R = Cn; Cc = 160;
    } else if (z == 6) {
        if (blockIdx.y >= 5) return;       // R=160 -> 5 row-tiles
        W = W6; Wt = T6; R = 160; Cc = Cn;
    } else {
        if (blockIdx.y >= 2) return;       // R=64 -> 2 row-tiles
        W = W7; Wt = T7; R = 64; Cc = Cn;
    }
    __shared__ float tile[32][33];
    int c0 = blockIdx.x * 32, r0 = blockIdx.y * 32;
    int tx = threadIdx.x & 31, ty = threadIdx.x >> 5;
    #pragma unroll
    for (int i = 0; i < 4; i++)
        tile[ty + 8 * i][tx] = W[(size_t)(r0 + ty + 8 * i) * Cc + c0 + tx];
    __syncthreads();
    #pragma unroll
    for (int i = 0; i < 4; i++)
        Wt[(size_t)(c0 + ty + 8 * i) * R + r0 + tx] = __float2bfloat16(tile[tx][ty + 8 * i]);
}

// ---------------------------------------------------------------------------
// Split-K f32 GEMM for the decay LoRA1 ([4096,1024]@[1024,64], N==64).
// ---------------------------------------------------------------------------
template <int KS>
__global__ __launch_bounds__(256) void gemm_f32_splitk(const float* __restrict__ A,
                                                       const float* __restrict__ Bm,
                                                       float* __restrict__ part,
                                                       int M, int N, int K) {
    __shared__ float As[16][64];
    __shared__ float Bs[16][64];
    int tid = threadIdx.x;
    int kp = blockIdx.x;
    int m0 = blockIdx.y * 64;
    int kbeg = kp * (K / KS), kend = kbeg + K / KS;
    int tx = tid & 15, ty = tid >> 4;
    int ar = tid >> 2, ac = (tid & 3) * 4;
    int br = tid >> 4, bc = (tid & 15) * 4;
    float acc[4][4] = {};

    for (int k0 = kbeg; k0 < kend; k0 += 16) {
        float4 av = *reinterpret_cast<const float4*>(A + (size_t)(m0 + ar) * K + k0 + ac);
        As[ac + 0][ar] = av.x; As[ac + 1][ar] = av.y;
        As[ac + 2][ar] = av.z; As[ac + 3][ar] = av.w;
        *reinterpret_cast<float4*>(&Bs[br][bc]) =
            *reinterpret_cast<const float4*>(Bm + (size_t)(k0 + br) * N + bc);
        __syncthreads();
        #pragma unroll
        for (int kk = 0; kk < 16; kk++) {
            float4 a4 = *reinterpret_cast<const float4*>(&As[kk][ty * 4]);
            float4 b4 = *reinterpret_cast<const float4*>(&Bs[kk][tx * 4]);
            float aa[4] = {a4.x, a4.y, a4.z, a4.w};
            float bb[4] = {b4.x, b4.y, b4.z, b4.w};
            #pragma unroll
            for (int i = 0; i < 4; i++)
                #pragma unroll
                for (int j = 0; j < 4; j++)
                    acc[i][j] = fmaf(aa[i], bb[j], acc[i][j]);
        }
        __syncthreads();
    }
    #pragma unroll
    for (int i = 0; i < 4; i++) {
        int row = m0 + ty * 4 + i;
        #pragma unroll
        for (int j = 0; j < 4; j++)
            part[((size_t)kp * M + row) * N + tx * 4 + j] = acc[i][j];
    }
}

// Reduce KS partials + tanh -> bf16
template <int KS>
__global__ __launch_bounds__(256) void splitk_reduce_tanh_bf(const float* __restrict__ part,
                                                             __hip_bfloat16* __restrict__ outp,
                                                             int total, size_t stride) {
    int i = blockIdx.x * 256 + threadIdx.x;
    if (i >= total) return;
    float s = 0.f;
    #pragma unroll
    for (int kp = 0; kp < KS; kp++) s += part[kp * stride + i];
    outp[i] = __float2bfloat16(tanhf(s));
}

// ---------------------------------------------------------------------------
// Split-K bf16 MFMA GEMM for token-mix LoRA1 ([4096,1024]@[1024,160]) with
// FUSED mix-input staging: A[row][k] = bf16(x + (x_prev - x)*x_maa[k]).
// ---------------------------------------------------------------------------
template <int KS>
__global__ __launch_bounds__(256) void gemm_mfma_sk(const float* __restrict__ x,
                                                    const float* __restrict__ x_maa,
                                                    const __hip_bfloat16* __restrict__ Bt,
                                                    float* __restrict__ part,
                                                    int M, int N, int K) {
    __shared__ alignas(16) unsigned short As[64 * 64];
    __shared__ alignas(16) unsigned short Bs[128 * 64];
    int tid = threadIdx.x;
    int m0 = blockIdx.y * 64, n0 = blockIdx.x * 128;
    int kp = blockIdx.z;
    int kbeg = kp * (K / KS), kend = kbeg + K / KS;
    int wave = tid >> 6, lane = tid & 63;
    int wm = (wave & 1) * 32, wn = (wave >> 1) * 64;
    int l15 = lane & 15, l4 = lane >> 4;
    f32x4_t acc[2][4] = {};

    for (int k0 = kbeg; k0 < kend; k0 += 64) {
        #pragma unroll
        for (int p = 0; p < 2; p++) {
            int cch = tid + p * 256;
            int row = cch >> 3, slot = cch & 7;
            int s2 = slot ^ (row & 7);
            int gr = m0 + row;
            int t = gr & (Tn - 1);
            size_t gx = (size_t)gr * Cn + k0 + slot * 8;
            float4 xa0 = *reinterpret_cast<const float4*>(x + gx);
            float4 xa1 = *reinterpret_cast<const float4*>(x + gx + 4);
            float4 xp0 = make_float4(0.f, 0.f, 0.f, 0.f), xp1 = xp0;
            if (t > 0) {
                xp0 = *reinterpret_cast<const float4*>(x + gx - Cn);
                xp1 = *reinterpret_cast<const float4*>(x + gx - Cn + 4);
            }
            float4 ma0 = *reinterpret_cast<const float4*>(x_maa + k0 + slot * 8);
            float4 ma1 = *reinterpret_cast<const float4*>(x_maa + k0 + slot * 8 + 4);
            ushort4 o0, o1;
            o0.x = f2bf_bits(xa0.x + (xp0.x - xa0.x) * ma0.x);
            o0.y = f2bf_bits(xa0.y + (xp0.y - xa0.y) * ma0.y);
            o0.z = f2bf_bits(xa0.z + (xp0.z - xa0.z) * ma0.z);
            o0.w = f2bf_bits(xa0.w + (xp0.w - xa0.w) * ma0.w);
            o1.x = f2bf_bits(xa1.x + (xp1.x - xa1.x) * ma1.x);
            o1.y = f2bf_bits(xa1.y + (xp1.y - xa1.y) * ma1.y);
            o1.z = f2bf_bits(xa1.z + (xp1.z - xa1.z) * ma1.z);
            o1.w = f2bf_bits(xa1.w + (xp1.w - xa1.w) * ma1.w);
            *reinterpret_cast<ushort4*>(&As[row * 64 + s2 * 8]) = o0;
            *reinterpret_cast<ushort4*>(&As[row * 64 + s2 * 8 + 4]) = o1;
        }
        #pragma unroll
        for (int p = 0; p < 4; p++) {
            int cch = tid + p * 256;
            int row = cch >> 3, slot = cch & 7;
            int s2 = slot ^ (row & 7);
            int rowg = n0 + row; if (rowg > N - 1) rowg = N - 1;  // clamp
            *reinterpret_cast<us8_t*>(&Bs[row * 64 + s2 * 8]) =
                *reinterpret_cast<const us8_t*>(&Bt[(size_t)rowg * K + k0 + slot * 8]);
        }
        __syncthreads();
        #pragma unroll
        for (int kw = 0; kw < 2; kw++) {
            int slot = kw * 4 + l4;
            bf16x8_t af[2], bfr[4];
            #pragma unroll
            for (int f = 0; f < 2; f++) {
                int ar = wm + f * 16 + l15;
                af[f] = *reinterpret_cast<const bf16x8_t*>(&As[ar * 64 + (slot ^ (ar & 7)) * 8]);
            }
            #pragma unroll
            for (int f = 0; f < 4; f++) {
                int br = wn + f * 16 + l15;
                bfr[f] = *reinterpret_cast<const bf16x8_t*>(&Bs[br * 64 + (slot ^ (br & 7)) * 8]);
            }
            #pragma unroll
            for (int i = 0; i < 2; i++)
                #pragma unroll
                for (int j = 0; j < 4; j++)
                    acc[i][j] = __builtin_amdgcn_mfma_f32_16x16x32_bf16(af[i], bfr[j], acc[i][j], 0, 0, 0);
        }
        __syncthreads();
    }

    #pragma unroll
    for (int i = 0; i < 2; i++) {
        int rbase = m0 + wm + i * 16 + l4 * 4;
        #pragma unroll
        for (int j = 0; j < 4; j++) {
            int col = n0 + wn + j * 16 + l15;
            if (col < N) {
                #pragma unroll
                for (int q = 0; q < 4; q++)
                    part[((size_t)kp * M + rbase + q) * N + col] = acc[i][j][q];
            }
        }
    }
}

// ---------------------------------------------------------------------------
// Deltas GEMM + FUSED token-shift mix (batched over f=blockIdx.z).
// ---------------------------------------------------------------------------
__global__ __launch_bounds__(256) void dmix_gemm(const __hip_bfloat16* __restrict__ A,
                                                 const __hip_bfloat16* __restrict__ W2T,
                                                 const float* __restrict__ x,
                                                 const float* __restrict__ wmaa,
                                                 const float* __restrict__ kmaa,
                                                 const float* __restrict__ vmaa,
                                                 const float* __restrict__ rmaa,
                                                 const float* __restrict__ gmaa,
                                                 float* __restrict__ wx,
                                                 __hip_bfloat16* __restrict__ kxb,
                                                 __hip_bfloat16* __restrict__ vxb,
                                                 __hip_bfloat16* __restrict__ rxb,
                                                 __hip_bfloat16* __restrict__ gxb) {
    __shared__ alignas(16) unsigned short As[64 * 32];
    __shared__ alignas(16) unsigned short Bs[128 * 32];
    int tid = threadIdx.x;
    int m0 = blockIdx.x * 64, n0 = blockIdx.y * 128;   // m fastest -> XCD=m%8
    int f  = blockIdx.z;
    int wave = tid >> 6, lane = tid & 63;
    int wm = (wave & 1) * 32, wn = (wave >> 1) * 64;
    int l15 = lane & 15, l4 = lane >> 4;
    int lrow2 = lane >> 2, ls = lane & 3;   // 16 rows x 4 slots per gload
    f32x4_t acc[2][4] = {};

    {
        int row = wave * 16 + lrow2;
        int gs = ls ^ (row & 3);
        gload16(&A[(size_t)(m0 + row) * 160 + f * 32 + gs * 8], &As[(wave * 16) * 32]);
    }
    #pragma unroll
    for (int ci = 0; ci < 2; ci++) {
        int r0 = wave * 32 + ci * 16;
        int row = r0 + lrow2;
        int gs = ls ^ (row & 3);
        gload16(&W2T[(size_t)(n0 + row) * 160 + f * 32 + gs * 8], &Bs[r0 * 32]);
    }
    __syncthreads();
    bf16x8_t af[2], bfr[4];
    #pragma unroll
    for (int i = 0; i < 2; i++) {
        int ar = wm + i * 16 + l15;
        af[i] = *reinterpret_cast<const bf16x8_t*>(&As[ar * 32 + ((l4 ^ (ar & 3)) * 8)]);
    }
    #pragma unroll
    for (int j = 0; j < 4; j++) {
        int br = wn + j * 16 + l15;
        bfr[j] = *reinterpret_cast<const bf16x8_t*>(&Bs[br * 32 + ((l4 ^ (br & 3)) * 8)]);
    }
    #pragma unroll
    for (int i = 0; i < 2; i++)
        #pragma unroll
        for (int j = 0; j < 4; j++)
            acc[i][j] = __builtin_amdgcn_mfma_f32_16x16x32_bf16(af[i], bfr[j], acc[i][j], 0, 0, 0);

    const float* maa = (f == 0) ? wmaa : (f == 1) ? kmaa : (f == 2) ? vmaa
                     : (f == 3) ? rmaa : gmaa;
    __hip_bfloat16* dstb = (f == 1) ? kxb : (f == 2) ? vxb : (f == 3) ? rxb : gxb;
    #pragma unroll
    for (int i = 0; i < 2; i++) {
        int rbase = m0 + wm + i * 16 + l4 * 4;
        #pragma unroll
        for (int j = 0; j < 4; j++) {
            int col = n0 + wn + j * 16 + l15;
            float mv = maa[col];
            #pragma unroll
            for (int q = 0; q < 4; q++) {
                int row = rbase + q;
                int t = row & (Tn - 1);
                size_t o = (size_t)row * Cn + col;
                float xv = x[o];
                float xp = (t > 0) ? x[o - Cn] : 0.f;
                float val = xv + (xp - xv) * (mv + acc[i][j][q]);
                if (f == 0) wx[o] = val;
                else        dstb[o] = __float2bfloat16(val);
            }
        }
    }
}

// ---------------------------------------------------------------------------
// GROUPED bf16 MFMA GEMM (16x16x32): 4 projections (r,k,v,g) in ONE dispatch.
// ---------------------------------------------------------------------------
__global__ __launch_bounds__(256) void gemm_qkvg(const __hip_bfloat16* __restrict__ A0,
                                                 const __hip_bfloat16* __restrict__ A1,
                                                 const __hip_bfloat16* __restrict__ A2,
                                                 const __hip_bfloat16* __restrict__ A3,
                                                 const __hip_bfloat16* __restrict__ B0,
                                                 const __hip_bfloat16* __restrict__ B1,
                                                 const __hip_bfloat16* __restrict__ B2,
                                                 const __hip_bfloat16* __restrict__ B3,
                                                 __hip_bfloat16* __restrict__ C0,
                                                 __hip_bfloat16* __restrict__ C1,
                                                 __hip_bfloat16* __restrict__ C2,
                                                 __hip_bfloat16* __restrict__ C3,
                                                 int M, int N, int K) {
    int g = blockIdx.z;
    const __hip_bfloat16* A  = (g == 0) ? A0 : (g == 1) ? A1 : (g == 2) ? A2 : A3;
    const __hip_bfloat16* Bt = (g == 0) ? B0 : (g == 1) ? B1 : (g == 2) ? B2 : B3;
    __hip_bfloat16* Co = (g == 0) ? C0 : (g == 1) ? C1 : (g == 2) ? C2 : C3;
    __shared__ alignas(16) unsigned short As[64 * 64];
    __shared__ alignas(16) unsigned short Bs[128 * 64];
    int tid = threadIdx.x;
    int m0 = blockIdx.x * 64, n0 = blockIdx.y * 128;   // m fastest -> XCD=m%8
    int wave = tid >> 6, lane = tid & 63;
    int wm = (wave & 1) * 32, wn = (wave >> 1) * 64;
    int l15 = lane & 15, l4 = lane >> 4;
    int lrow = lane >> 3, ls2 = lane & 7;
    f32x4_t acc[2][4] = {};

    for (int k0 = 0; k0 < K; k0 += 64) {
        #pragma unroll
        for (int ci = 0; ci < 2; ci++) {
            int r0 = wave * 16 + ci * 8;
            int row = r0 + lrow;
            int gs = ls2 ^ (row & 7);
            gload16(&A[(size_t)(m0 + row) * K + k0 + gs * 8], &As[r0 * 64]);
        }
        #pragma unroll
        for (int ci = 0; ci < 4; ci++) {
            int r0 = wave * 32 + ci * 8;
            int row = r0 + lrow;
            int gs = ls2 ^ (row & 7);
            gload16(&Bt[(size_t)(n0 + row) * K + k0 + gs * 8], &Bs[r0 * 64]);
        }
        __syncthreads();
        #pragma unroll
        for (int kw = 0; kw < 2; kw++) {
            int slot = kw * 4 + l4;
            bf16x8_t af[2], bfr[4];
            #pragma unroll
            for (int f = 0; f < 2; f++) {
                int ar = wm + f * 16 + l15;
                af[f] = *reinterpret_cast<const bf16x8_t*>(&As[ar * 64 + (slot ^ (ar & 7)) * 8]);
            }
            #pragma unroll
            for (int f = 0; f < 4; f++) {
                int br = wn + f * 16 + l15;
                bfr[f] = *reinterpret_cast<const bf16x8_t*>(&Bs[br * 64 + (slot ^ (br & 7)) * 8]);
            }
            #pragma unroll
            for (int i = 0; i < 2; i++)
                #pragma unroll
                for (int j = 0; j < 4; j++)
                    acc[i][j] = __builtin_amdgcn_mfma_f32_16x16x32_bf16(af[i], bfr[j], acc[i][j], 0, 0, 0);
        }
        __syncthreads();
    }

    #pragma unroll
    for (int i = 0; i < 2; i++) {
        int rbase = m0 + wm + i * 16 + l4 * 4;
        #pragma unroll
        for (int j = 0; j < 4; j++) {
            int col = n0 + wn + j * 16 + l15;
            #pragma unroll
            for (int q = 0; q < 4; q++) {
                float v = acc[i][j][q];
                if (g == 3) v = v / (1.f + expf(-v));
                Co[(size_t)(rbase + q) * N + col] = __float2bfloat16(v);
            }
        }
    }
}

// Wo projection (single, gl-staged, 64x128 tile, m-fastest grid), f32 out
__global__ __launch_bounds__(256) void gemm_mfma_gl(const __hip_bfloat16* __restrict__ A,
                                                    const __hip_bfloat16* __restrict__ Bt,
                                                    float* __restrict__ Cout,
                                                    int M, int N, int K) {
    __shared__ alignas(16) unsigned short As[64 * 64];
    __shared__ alignas(16) unsigned short Bs[128 * 64];
    int tid = threadIdx.x;
    int m0 = blockIdx.x * 64, n0 = blockIdx.y * 128;   // m fastest -> XCD=m%8
    int wave = tid >> 6, lane = tid & 63;
    int wm = (wave & 1) * 32, wn = (wave >> 1) * 64;
    int l15 = lane & 15, l4 = lane >> 4;
    int lrow = lane >> 3, ls2 = lane & 7;
    f32x4_t acc[2][4] = {};

    for (int k0 = 0; k0 < K; k0 += 64) {
        #pragma unroll
        for (int ci = 0; ci < 2; ci++) {
            int r0 = wave * 16 + ci * 8;
            int row = r0 + lrow;
            int gs = ls2 ^ (row & 7);
            gload16(&A[(size_t)(m0 + row) * K + k0 + gs * 8], &As[r0 * 64]);
        }
        #pragma unroll
        for (int ci = 0; ci < 4; ci++) {
            int r0 = wave * 32 + ci * 8;
            int row = r0 + lrow;
            int gs = ls2 ^ (row & 7);
            gload16(&Bt[(size_t)(n0 + row) * K + k0 + gs * 8], &Bs[r0 * 64]);
        }
        __syncthreads();
        #pragma unroll
        for (int kw = 0; kw < 2; kw++) {
            int slot = kw * 4 + l4;
            bf16x8_t af[2], bfr[4];
            #pragma unroll
            for (int f = 0; f < 2; f++) {
                int ar = wm + f * 16 + l15;
                af[f] = *reinterpret_cast<const bf16x8_t*>(&As[ar * 64 + (slot ^ (ar & 7)) * 8]);
            }
            #pragma unroll
            for (int f = 0; f < 4; f++) {
                int br = wn + f * 16 + l15;
                bfr[f] = *reinterpret_cast<const bf16x8_t*>(&Bs[br * 64 + (slot ^ (br & 7)) * 8]);
            }
            #pragma unroll
            for (int i = 0; i < 2; i++)
                #pragma unroll
                for (int j = 0; j < 4; j++)
                    acc[i][j] = __builtin_amdgcn_mfma_f32_16x16x32_bf16(af[i], bfr[j], acc[i][j], 0, 0, 0);
        }
        __syncthreads();
    }

    #pragma unroll
    for (int i = 0; i < 2; i++) {
        int rbase = m0 + wm + i * 16 + l4 * 4;
        #pragma unroll
        for (int j = 0; j < 4; j++) {
            int col = n0 + wn + j * 16 + l15;
            #pragma unroll
            for (int q = 0; q < 4; q++)
                Cout[(size_t)(rbase + q) * N + col] = acc[i][j][q];
        }
    }
}

// ---------------------------------------------------------------------------
// FUSED decay-tile computation (shared by chunk_summary / chunk_out):
// computes lw[t][ch] = -exp(t_dec[h*64+ch] + wl1b[t]@tdw2T[ch]) for this
// block's 64x64 tile via 8 MFMAs (direct-global fragments), writes into
// LDS linc[t][ch]. Caller must __syncthreads() after.
// wave covers t-strip [wave*16, wave*16+16).
// ---------------------------------------------------------------------------
__device__ __forceinline__ void decay_tile(const __hip_bfloat16* __restrict__ wl1b,
                                           const __hip_bfloat16* __restrict__ tdw2T,
                                           const float* __restrict__ t_dec,
                                           int h, size_t row0,   // global t row base
                                           float linc[64][68],
                                           int wave, int lane) {
    int l15 = lane & 15, l4 = lane >> 4;
    #pragma unroll
    for (int nt = 0; nt < 4; nt++) {
        f32x4_t acc = {};
        #pragma unroll
        for (int kw = 0; kw < 2; kw++) {
            int arow = row0 + wave * 16 + l15;
            bf16x8_t a = *reinterpret_cast<const bf16x8_t*>(
                &wl1b[(size_t)arow * 64 + (kw * 4 + l4) * 8]);
            int bcol = h * 64 + nt * 16 + l15;
            bf16x8_t b = *reinterpret_cast<const bf16x8_t*>(
                &tdw2T[(size_t)bcol * 64 + (kw * 4 + l4) * 8]);
            acc = __builtin_amdgcn_mfma_f32_16x16x32_bf16(a, b, acc, 0, 0, 0);
        }
        #pragma unroll
        for (int q = 0; q < 4; q++) {
            int t = wave * 16 + l4 * 4 + q;
            int ch = nt * 16 + l15;
            linc[t][ch] = -expf(t_dec[h * 64 + ch] + acc[q]);
        }
    }
}

// In-LDS prefix sum over t (lane = channel), wave covers 16 t-rows.
__device__ __forceinline__ void prefix_lds(float linc[64][68], float wtp[4][64],
                                           int wave, int lane) {
    float acc = 0.f;
    #pragma unroll
    for (int i = 0; i < 16; i++) {
        acc += linc[wave * 16 + i][lane];
        linc[wave * 16 + i][lane] = acc;
    }
    wtp[wave][lane] = acc;
    __syncthreads();
    float off = 0.f;
    for (int g = 0; g < wave; g++) off += wtp[g][lane];
    #pragma unroll
    for (int i = 0; i < 16; i++) linc[wave * 16 + i][lane] += off;
}

// ---------------------------------------------------------------------------
// Chunked WKV stage A (MFMA) with FUSED decay tile: per (b,h,chunk).
// ---------------------------------------------------------------------------
__global__ __launch_bounds__(256) void chunk_summary(const __hip_bfloat16* __restrict__ kb,
                                                     const __hip_bfloat16* __restrict__ vb,
                                                     const __hip_bfloat16* __restrict__ wl1b,
                                                     const __hip_bfloat16* __restrict__ tdw2T,
                                                     const float* __restrict__ t_dec,
                                                     __hip_bfloat16* __restrict__ Bc,
                                                     float* __restrict__ Wtot) {
    int bid = blockIdx.x;
    int c = bid & 15, h = (bid >> 4) & 15, b = bid >> 8;
    size_t row0 = (size_t)(b * Tn + c * CL);
    size_t gbase = row0 * Cn + (size_t)h * 64;
    int tid = threadIdx.x;
    __shared__ float linc[64][68];
    __shared__ float wtp[4][64];
    __shared__ alignas(16) __hip_bfloat16 kdT[64][72];  // [ch][tau]
    __shared__ alignas(16) __hip_bfloat16 vsT[64][72];  // [v][tau]
    int wave = tid >> 6, lane = tid & 63;
    // Phase 0: decay tile (MFMA) -> linc holds lw values
    decay_tile(wl1b, tdw2T, t_dec, h, row0, linc, wave, lane);
    __syncthreads();
    // Phase 1: prefix sum over t
    prefix_lds(linc, wtp, wave, lane);
    __syncthreads();
    int t4 = tid >> 2, c0 = (tid & 3) * 16;
    #pragma unroll
    for (int i = 0; i < 4; i++) {
        int ch = c0 + i * 4;
        size_t ga = gbase + (size_t)t4 * 1024 + ch;
        ushort4 ku = *reinterpret_cast<const ushort4*>(kb + ga);
        ushort4 vu = *reinterpret_cast<const ushort4*>(vb + ga);
        float kk[4] = {bfbits2f(ku.x), bfbits2f(ku.y), bfbits2f(ku.z), bfbits2f(ku.w)};
        float vv[4] = {bfbits2f(vu.x), bfbits2f(vu.y), bfbits2f(vu.z), bfbits2f(vu.w)};
        #pragma unroll
        for (int j = 0; j < 4; j++) {
            float li = linc[t4][ch + j];
            float lend = linc[63][ch + j];
            kdT[ch + j][t4] = __float2bfloat16(kk[j] * expf(lend - li));
            vsT[ch + j][t4] = __float2bfloat16(vv[j]);
        }
    }
    if (tid < 64) Wtot[(size_t)bid * 64 + tid] = expf(linc[63][tid]);
    __syncthreads();
    int l15 = lane & 15, l4q = lane >> 4;
    #pragma unroll
    for (int nt = 0; nt < 4; nt++) {
        f32x4_t acc = {};
        #pragma unroll
        for (int kt = 0; kt < 2; kt++) {
            bf16x8_t a = *reinterpret_cast<const bf16x8_t*>(&kdT[wave * 16 + l15][kt * 32 + l4q * 8]);
            bf16x8_t bb = *reinterpret_cast<const bf16x8_t*>(&vsT[nt * 16 + l15][kt * 32 + l4q * 8]);
            acc = __builtin_amdgcn_mfma_f32_16x16x32_bf16(a, bb, acc, 0, 0, 0);
        }
        #pragma unroll
        for (int q = 0; q < 4; q++) {
            int krow = wave * 16 + l4q * 4 + q;
            Bc[(size_t)bid * 4096 + (size_t)krow * 64 + nt * 16 + l15] = __float2bfloat16(acc[q]);
        }
    }
}

// ---------------------------------------------------------------------------
// Stage B: sequential scan over NC=16 chunk states (f32 accum internally).
// ---------------------------------------------------------------------------
__global__ __launch_bounds__(256) void chunk_scan(const __hip_bfloat16* __restrict__ Bc,
                                                  const float* __restrict__ Wtot,
                                                  __hip_bfloat16* __restrict__ SbufT) {
    int bid = blockIdx.x;
    int bh = bid >> 2, vg = bid & 3;
    int kk = threadIdx.x >> 2;
    int v = vg * 16 + (threadIdx.x & 3) * 4;
    float4 S = make_float4(0.f, 0.f, 0.f, 0.f);
    for (int c = 0; c < NC; c++) {
        size_t base = (size_t)(bh * NC + c) * 4096;
        SbufT[base + (size_t)(v + 0) * 64 + kk] = __float2bfloat16(S.x);
        SbufT[base + (size_t)(v + 1) * 64 + kk] = __float2bfloat16(S.y);
        SbufT[base + (size_t)(v + 2) * 64 + kk] = __float2bfloat16(S.z);
        SbufT[base + (size_t)(v + 3) * 64 + kk] = __float2bfloat16(S.w);
        float wt = Wtot[(size_t)(bh * NC + c) * 64 + kk];
        ushort4 b4 = *reinterpret_cast<const ushort4*>(Bc + base + (size_t)kk * 64 + v);
        S.x = fmaf(wt, S.x, bfbits2f(b4.x));
        S.y = fmaf(wt, S.y, bfbits2f(b4.y));
        S.z = fmaf(wt, S.z, bfbits2f(b4.z));
        S.w = fmaf(wt, S.w, bfbits2f(b4.w));
    }
}

// ---------------------------------------------------------------------------
// Stage C (MFMA) with FUSED decay tile + FUSED GroupNorm*g.
// qs uses EXCLUSIVE prefix: exp(linc[t-1]) (== exp(li - lw[t])).
// ---------------------------------------------------------------------------
__global__ __launch_bounds__(256) void chunk_out(const __hip_bfloat16* __restrict__ rb,
                                                 const __hip_bfloat16* __restrict__ kb,
                                                 const __hip_bfloat16* __restrict__ vb,
                                                 const __hip_bfloat16* __restrict__ wl1b,
                                                 const __hip_bfloat16* __restrict__ tdw2T,
                                                 const float* __restrict__ t_dec,
                                                 const __hip_bfloat16* __restrict__ SbufT,
                                                 const float* __restrict__ tf,
                                                 const __hip_bfloat16* __restrict__ gb,
                                                 const float* __restrict__ lnw,
                                                 const float* __restrict__ lnb,
                                                 __hip_bfloat16* __restrict__ fin) {
    int bid = blockIdx.x;
    int c = bid & 15, h = (bid >> 4) & 15, b = bid >> 8;
    size_t row0 = (size_t)(b * Tn + c * CL);
    size_t gbase = row0 * Cn + (size_t)h * 64;
    int tid = threadIdx.x;
    __shared__ alignas(16) __hip_bfloat16 qs[64][72];   // [t][ch]
    __shared__ alignas(16) __hip_bfloat16 ks[64][72];   // [tau][ch]
    __shared__ alignas(16) __hip_bfloat16 vsT[64][72];  // [v][tau]
    __shared__ alignas(16) __hip_bfloat16 scT[64][72];  // [v][ch]
    __shared__ alignas(16) float uni[64 * 68];          // linc, then asb
    __shared__ float wtp[4][64];
    __shared__ float diag[64];
    float (*linc)[68] = reinterpret_cast<float(*)[68]>(uni);
    __hip_bfloat16 (*asb)[72] = reinterpret_cast<__hip_bfloat16(*)[72]>(uni);
    int wave = tid >> 6, lane = tid & 63;
    // Phase 0: decay tile (MFMA) -> linc holds lw values; then prefix
    decay_tile(wl1b, tdw2T, t_dec, h, row0, linc, wave, lane);
    __syncthreads();
    prefix_lds(linc, wtp, wave, lane);
    __syncthreads();
    int t4 = tid >> 2, c0 = (tid & 3) * 16;
    float dpart = 0.f;
    #pragma unroll
    for (int i = 0; i < 4; i++) {
        int ch = c0 + i * 4;
        size_t ga = gbase + (size_t)t4 * 1024 + ch;
        ushort4 ru = *reinterpret_cast<const ushort4*>(rb + ga);
        ushort4 ku = *reinterpret_cast<const ushort4*>(kb + ga);
        ushort4 vu = *reinterpret_cast<const ushort4*>(vb + ga);
        float4 u4 = *reinterpret_cast<const float4*>(tf + h * 64 + ch);
        ushort4 s4 = *reinterpret_cast<const ushort4*>(SbufT + (size_t)bid * 4096 + (size_t)t4 * 64 + ch);
        float rr[4] = {bfbits2f(ru.x), bfbits2f(ru.y), bfbits2f(ru.z), bfbits2f(ru.w)};
        float kkv[4] = {bfbits2f(ku.x), bfbits2f(ku.y), bfbits2f(ku.z), bfbits2f(ku.w)};
        float vv[4] = {bfbits2f(vu.x), bfbits2f(vu.y), bfbits2f(vu.z), bfbits2f(vu.w)};
        float uu[4] = {u4.x, u4.y, u4.z, u4.w};
        unsigned short ssb[4] = {s4.x, s4.y, s4.z, s4.w};
        #pragma unroll
        for (int j = 0; j < 4; j++) {
            float li = linc[t4][ch + j];
            float lex = (t4 > 0) ? linc[t4 - 1][ch + j] : 0.f;   // exclusive prefix
            qs[t4][ch + j] = __float2bfloat16(rr[j] * expf(lex));
            ks[t4][ch + j] = __float2bfloat16(kkv[j] * expf(-li));
            vsT[ch + j][t4] = __float2bfloat16(vv[j]);
            *reinterpret_cast<unsigned short*>(&scT[t4][ch + j]) = ssb[j];   // row t4 = v
            dpart = fmaf(rr[j] * uu[j], kkv[j], dpart);
        }
    }
    dpart += __shfl_xor(dpart, 1);
    dpart += __shfl_xor(dpart, 2);
    if ((tid & 3) == 0) diag[t4] = dpart;
    __syncthreads();        // linc dead; asb may now overwrite uni
    int l15 = lane & 15, l4q = lane >> 4;
    #pragma unroll
    for (int nt = 0; nt < 4; nt++) {
        f32x4_t acc = {};
        if (nt <= wave) {
            #pragma unroll
            for (int kt = 0; kt < 2; kt++) {
                bf16x8_t a = *reinterpret_cast<const bf16x8_t*>(&qs[wave * 16 + l15][kt * 32 + l4q * 8]);
                bf16x8_t bb = *reinterpret_cast<const bf16x8_t*>(&ks[nt * 16 + l15][kt * 32 + l4q * 8]);
                acc = __builtin_amdgcn_mfma_f32_16x16x32_bf16(a, bb, acc, 0, 0, 0);
            }
        }
        #pragma unroll
        for (int q = 0; q < 4; q++) {
            int t = wave * 16 + l4q * 4 + q;
            int tau = nt * 16 + l15;
            float v = (tau < t) ? acc[q] : (tau == t ? diag[t] : 0.f);
            asb[t][tau] = __float2bfloat16(v);
        }
    }
    __syncthreads();
    // PV + state matmuls -> keep in regs for fused GN
    f32x4_t oacc[4];
    #pragma unroll
    for (int nt = 0; nt < 4; nt++) {
        f32x4_t acc = {};
        int kmax = (wave >> 1) + 1;
        for (int kt = 0; kt < kmax; kt++) {
            bf16x8_t a = *reinterpret_cast<const bf16x8_t*>(&asb[wave * 16 + l15][kt * 32 + l4q * 8]);
            bf16x8_t bb = *reinterpret_cast<const bf16x8_t*>(&vsT[nt * 16 + l15][kt * 32 + l4q * 8]);
            acc = __builtin_amdgcn_mfma_f32_16x16x32_bf16(a, bb, acc, 0, 0, 0);
        }
        #pragma unroll
        for (int kt = 0; kt < 2; kt++) {
            bf16x8_t a = *reinterpret_cast<const bf16x8_t*>(&qs[wave * 16 + l15][kt * 32 + l4q * 8]);
            bf16x8_t bb = *reinterpret_cast<const bf16x8_t*>(&scT[nt * 16 + l15][kt * 32 + l4q * 8]);
            acc = __builtin_amdgcn_mfma_f32_16x16x32_bf16(a, bb, acc, 0, 0, 0);
        }
        oacc[nt] = acc;
    }
    // Fused GroupNorm
    float sum[4] = {0.f, 0.f, 0.f, 0.f}, sq[4] = {0.f, 0.f, 0.f, 0.f};
    #pragma unroll
    for (int nt = 0; nt < 4; nt++)
        #pragma unroll
        for (int q = 0; q < 4; q++) {
            float v = oacc[nt][q] * 0.125f;   // / head_size_divisor
            oacc[nt][q] = v;
            sum[q] += v;
            sq[q] += v * v;
        }
    #pragma unroll
    for (int off = 1; off < 16; off <<= 1)
        #pragma unroll
        for (int q = 0; q < 4; q++) {
            sum[q] += __shfl_xor(sum[q], off, 64);
            sq[q]  += __shfl_xor(sq[q],  off, 64);
        }
    float mu[4], rs[4];
    #pragma unroll
    for (int q = 0; q < 4; q++) {
        mu[q] = sum[q] * (1.f / 64.f);
        float var = sq[q] * (1.f / 64.f) - mu[q] * mu[q];
        rs[q] = rsqrtf(var + 1e-5f);
    }
    #pragma unroll
    for (int nt = 0; nt < 4; nt++) {
        int v = nt * 16 + l15;
        float lw_ = lnw[h * 64 + v];
        float lb_ = lnb[h * 64 + v];
        #pragma unroll
        for (int q = 0; q < 4; q++) {
            int t = wave * 16 + l4q * 4 + q;
            size_t o = gbase + (size_t)t * 1024 + v;
            float gv = bfbits2f(*reinterpret_cast<const unsigned short*>(&gb[o]));
            float val = (oacc[nt][q] - mu[q]) * rs[q] * lw_ + lb_;
            fin[o] = __float2bfloat16(val * gv);
        }
    }
}

// ---------------------------------------------------------------------------
extern "C" void kernel_launch(void* const* d_in, const int* in_sizes, int n_in,
                              void* d_out, int out_size, void* d_ws, size_t ws_size,
                              hipStream_t stream) {
    (void)in_sizes; (void)n_in; (void)out_size; (void)ws_size;
    const float* x      = (const float*)d_in[0];
    const float* x_maa  = (const float*)d_in[1];
    const float* w_maa  = (const float*)d_in[2];
    const float* k_maa  = (const float*)d_in[3];
    const float* v_maa  = (const float*)d_in[4];
    const float* r_maa  = (const float*)d_in[5];
    const float* g_maa  = (const float*)d_in[6];
    const float* tm_w1  = (const float*)d_in[7];
    const float* tm_w2  = (const float*)d_in[8];
    const float* td_w1  = (const float*)d_in[9];
    const float* td_w2  = (const float*)d_in[10];
    const float* t_dec  = (const float*)d_in[11];
    const float* t_first= (const float*)d_in[12];
    const float* Wr     = (const float*)d_in[13];
    const float* Wk     = (const float*)d_in[14];
    const float* Wv     = (const float*)d_in[15];
    const float* Wg     = (const float*)d_in[16];
    const float* Wo     = (const float*)d_in[17];
    const float* ln_w   = (const float*)d_in[18];
    const float* ln_b   = (const float*)d_in[19];
    float* out = (float*)d_out;

    // Byte allocator, 256B aligned
    char* ws = (char*)d_ws;
    size_t off = 0;
    auto alloc = [&](size_t bytes) -> void* {
        void* p = ws + off;
        off = (off + bytes + 255) & ~(size_t)255;
        return p;
    };
    __hip_bfloat16* rb = (__hip_bfloat16*)alloc(BTC * 2);       // r projection
    __hip_bfloat16* mix160b = (__hip_bfloat16*)alloc((size_t)BT * 160 * 2);
    float* wxr    = (float*)alloc(BTC * 4);            // wx -> BcB (bf16, 8MB)
    __hip_bfloat16* kxb = (__hip_bfloat16*)alloc(BTC * 2);  // alias: fin
    __hip_bfloat16* vxb = (__hip_bfloat16*)alloc(BTC * 2);
    __hip_bfloat16* rxb = (__hip_bfloat16*)alloc(BTC * 2);  // alias: SbufT (bf16, 8MB)
    __hip_bfloat16* gxb = (__hip_bfloat16*)alloc(BTC * 2);
    __hip_bfloat16* kb  = (__hip_bfloat16*)alloc(BTC * 2);
    __hip_bfloat16* vb  = (__hip_bfloat16*)alloc(BTC * 2);
    __hip_bfloat16* gb  = (__hip_bfloat16*)alloc(BTC * 2);
    __hip_bfloat16* WrT = (__hip_bfloat16*)alloc((size_t)Cn * Cn * 2);
    __hip_bfloat16* WkT = (__hip_bfloat16*)alloc((size_t)Cn * Cn * 2);
    __hip_bfloat16* WvT = (__hip_bfloat16*)alloc((size_t)Cn * Cn * 2);
    __hip_bfloat16* WgT = (__hip_bfloat16*)alloc((size_t)Cn * Cn * 2);
    __hip_bfloat16* WoT = (__hip_bfloat16*)alloc((size_t)Cn * Cn * 2);
    __hip_bfloat16* tmw1T = (__hip_bfloat16*)alloc((size_t)160 * Cn * 2);
    __hip_bfloat16* w2T   = (__hip_bfloat16*)alloc((size_t)Cn * 160 * 2);
    __hip_bfloat16* tdw2T = (__hip_bfloat16*)alloc((size_t)Cn * 64 * 2);
    __hip_bfloat16* wl1b  = (__hip_bfloat16*)alloc((size_t)BT * 64 * 2);
    float* WtB = (float*)alloc((size_t)Bn * Hn * NC * 64 * 4);  // chunk decay totals
    // Time-shared region: lorapart (10.5MB) -> skpart (8MB), disjoint lifetimes
    char* big = (char*)alloc((size_t)4 * BT * 160 * 4);
    float* lorapart = (float*)big;             // [4][BT*160] f32
    float* skpart = (float*)big;               // [8][BT*64] f32
    // Aliases (stream-ordered; producers complete before reuse):
    __hip_bfloat16* BcB = (__hip_bfloat16*)wxr;   // chunk contributions (wx dead after splitk)
    __hip_bfloat16* SbufT = rxb;   // entry states (transposed, bf16; rxb dead after qkvg)
    __hip_bfloat16* fin = kxb;     // fused-GN output (kxb dead after projections)

    dim3 blk(256);
    // weight transpose+convert: ALL 8 weights in one dispatch
    transp8<<<dim3(32, 32, 8), blk, 0, stream>>>(Wr, Wk, Wv, Wg, Wo, tm_w1, tm_w2, td_w2,
                                                 WrT, WkT, WvT, WgT, WoT, tmw1T, w2T, tdw2T);
    // token-mix LoRA1 (bf16 MFMA split-K, FUSED mix staging; 512 blocks)
    gemm_mfma_sk<4><<<dim3(2, 64, 4), blk, 0, stream>>>(x, x_maa, tmw1T, lorapart, BT, 160, Cn);
    splitk_reduce_tanh_bf<4><<<dim3((BT * 160 + 255) / 256), blk, 0, stream>>>(
        lorapart, mix160b, BT * 160, (size_t)BT * 160);
    // deltas: batched MFMA GEMM with FUSED token-shift mix epilogue
    dmix_gemm<<<dim3(64, 8, 5), blk, 0, stream>>>(mix160b, w2T, x,
                                                  w_maa, k_maa, v_maa, r_maa, g_maa,
                                                  wxr, kxb, vxb, rxb, gxb);
    // projections: ONE grouped dispatch (r,k,v,g), 16x16x32 MFMA, m-fastest grid
    gemm_qkvg<<<dim3(64, 8, 4), blk, 0, stream>>>(rxb, kxb, vxb, gxb,
                                                  WrT, WkT, WvT, WgT,
                                                  rb, kb, vb, gb, BT, Cn, Cn);
    // decay LoRA1 (f32 split-K, 512 blocks) + fused reduce/tanh -> bf16
    gemm_f32_splitk<8><<<dim3(8, 64), blk, 0, stream>>>(wxr, td_w1, skpart, BT, 64, Cn);
    splitk_reduce_tanh_bf<8><<<dim3(BT * 64 / 256), blk, 0, stream>>>(skpart, wl1b, BT * 64,
                                                                      (size_t)BT * 64);
    // chunked scan (MFMA); decay tile fused into chunk kernels; GN fused in out
    chunk_summary<<<dim3(Bn * Hn * NC), blk, 0, stream>>>(kb, vb, wl1b, tdw2T, t_dec, BcB, WtB);
    chunk_scan<<<dim3(Bn * Hn * 4), blk, 0, stream>>>(BcB, WtB, SbufT);
    chunk_out<<<dim3(Bn * Hn * NC), blk, 0, stream>>>(rb, kb, vb, wl1b, tdw2T, t_dec,
                                                      SbufT, t_first, gb, ln_w, ln_b, fin);
    // output projection
    gemm_mfma_gl<<<dim3(64, 8), blk, 0, stream>>>(fin, WoT, out, BT, Cn, Cn);
}

// Round 21
// 183.892 us; speedup vs baseline: 1.0162x; 1.0162x over previous
//
#include <hip/hip_runtime.h>
#include <hip/hip_bf16.h>
#include <math.h>
#include <stdint.h>

// Problem constants
constexpr int Bn = 4, Tn = 1024, Cn = 1024, Hn = 16;
constexpr int BT = Bn * Tn;                 // 4096
constexpr long long BTC = (long long)BT * Cn;  // 4M elements
constexpr int CL = 64;                      // chunk length
constexpr int NC = Tn / CL;                 // 16 chunks

typedef __bf16 bf16x8_t __attribute__((ext_vector_type(8)));
typedef float f32x4_t __attribute__((ext_vector_type(4)));
typedef unsigned short us8_t __attribute__((ext_vector_type(8)));

__device__ __forceinline__ unsigned short f2bf_bits(float v) {
    __hip_bfloat16 h = __float2bfloat16(v);
    return *reinterpret_cast<unsigned short*>(&h);
}
__device__ __forceinline__ float bfbits2f(unsigned short u) {
    unsigned int x = (unsigned int)u << 16;
    return __uint_as_float(x);
}

// Direct global->LDS 16B/lane (wave-uniform LDS base + lane*16). CK-style casts.
__device__ __forceinline__ void gload16(const void* g, void* l) {
    auto const* gp = reinterpret_cast<const unsigned int __attribute__((address_space(1)))*>(
        reinterpret_cast<uintptr_t>(g));
    auto* lp = reinterpret_cast<unsigned int __attribute__((address_space(3)))*>(
        reinterpret_cast<uintptr_t>(l));
    __builtin_amdgcn_global_load_lds(gp, lp, 16, 0, 0);
}

// ---------------------------------------------------------------------------
// Transpose + convert, ALL 8 weights in one dispatch (z selects matrix).
// ---------------------------------------------------------------------------
__global__ __launch_bounds__(256) void transp8(const float* __restrict__ W0,
                                               const float* __restrict__ W1,
                                               const float* __restrict__ W2,
                                               const float* __restrict__ W3,
                                               const float* __restrict__ W4,
                                               const float* __restrict__ W5,
                                               const float* __restrict__ W6,
                                               const float* __restrict__ W7,
                                               __hip_bfloat16* __restrict__ T0,
                                               __hip_bfloat16* __restrict__ T1,
                                               __hip_bfloat16* __restrict__ T2,
                                               __hip_bfloat16* __restrict__ T3,
                                               __hip_bfloat16* __restrict__ T4,
                                               __hip_bfloat16* __restrict__ T5,
                                               __hip_bfloat16* __restrict__ T6,
                                               __hip_bfloat16* __restrict__ T7) {
    int z = blockIdx.z;
    const float* W;
    __hip_bfloat16* Wt;
    int R, Cc;
    if (z < 5) {
        W = (z == 0) ? W0 : (z == 1) ? W1 : (z == 2) ? W2 : (z == 3) ? W3 : W4;
        Wt = (z == 0) ? T0 : (z == 1) ? T1 : (z == 2) ? T2 : (z == 3) ? T3 : T4;
        R = Cn; Cc = Cn;
    } else if (z == 5) {
        if (blockIdx.x >= 5) return;       // Cc=160 -> 5 col-tiles
        W = W5; Wt = T5; R = Cn; Cc = 160;
    } else if (z == 6) {
        if (blockIdx.y >= 5) return;       // R=160 -> 5 row-tiles
        W = W6; Wt = T6; R = 160; Cc = Cn;
    } else {
        if (blockIdx.y >= 2) return;       // R=64 -> 2 row-tiles
        W = W7; Wt = T7; R = 64; Cc = Cn;
    }
    __shared__ float tile[32][33];
    int c0 = blockIdx.x * 32, r0 = blockIdx.y * 32;
    int tx = threadIdx.x & 31, ty = threadIdx.x >> 5;
    #pragma unroll
    for (int i = 0; i < 4; i++)
        tile[ty + 8 * i][tx] = W[(size_t)(r0 + ty + 8 * i) * Cc + c0 + tx];
    __syncthreads();
    #pragma unroll
    for (int i = 0; i < 4; i++)
        Wt[(size_t)(c0 + ty + 8 * i) * R + r0 + tx] = __float2bfloat16(tile[tx][ty + 8 * i]);
}

// ---------------------------------------------------------------------------
// Split-K f32 GEMM for the decay LoRA1 ([4096,1024]@[1024,64], N==64).
// ---------------------------------------------------------------------------
template <int KS>
__global__ __launch_bounds__(256) void gemm_f32_splitk(const float* __restrict__ A,
                                                       const float* __restrict__ Bm,
                                                       float* __restrict__ part,
                                                       int M, int N, int K) {
    __shared__ float As[16][64];
    __shared__ float Bs[16][64];
    int tid = threadIdx.x;
    int kp = blockIdx.x;
    int m0 = blockIdx.y * 64;
    int kbeg = kp * (K / KS), kend = kbeg + K / KS;
    int tx = tid & 15, ty = tid >> 4;
    int ar = tid >> 2, ac = (tid & 3) * 4;
    int br = tid >> 4, bc = (tid & 15) * 4;
    float acc[4][4] = {};

    for (int k0 = kbeg; k0 < kend; k0 += 16) {
        float4 av = *reinterpret_cast<const float4*>(A + (size_t)(m0 + ar) * K + k0 + ac);
        As[ac + 0][ar] = av.x; As[ac + 1][ar] = av.y;
        As[ac + 2][ar] = av.z; As[ac + 3][ar] = av.w;
        *reinterpret_cast<float4*>(&Bs[br][bc]) =
            *reinterpret_cast<const float4*>(Bm + (size_t)(k0 + br) * N + bc);
        __syncthreads();
        #pragma unroll
        for (int kk = 0; kk < 16; kk++) {
            float4 a4 = *reinterpret_cast<const float4*>(&As[kk][ty * 4]);
            float4 b4 = *reinterpret_cast<const float4*>(&Bs[kk][tx * 4]);
            float aa[4] = {a4.x, a4.y, a4.z, a4.w};
            float bb[4] = {b4.x, b4.y, b4.z, b4.w};
            #pragma unroll
            for (int i = 0; i < 4; i++)
                #pragma unroll
                for (int j = 0; j < 4; j++)
                    acc[i][j] = fmaf(aa[i], bb[j], acc[i][j]);
        }
        __syncthreads();
    }
    #pragma unroll
    for (int i = 0; i < 4; i++) {
        int row = m0 + ty * 4 + i;
        #pragma unroll
        for (int j = 0; j < 4; j++)
            part[((size_t)kp * M + row) * N + tx * 4 + j] = acc[i][j];
    }
}

// Reduce KS partials + tanh -> bf16
template <int KS>
__global__ __launch_bounds__(256) void splitk_reduce_tanh_bf(const float* __restrict__ part,
                                                             __hip_bfloat16* __restrict__ outp,
                                                             int total, size_t stride) {
    int i = blockIdx.x * 256 + threadIdx.x;
    if (i >= total) return;
    float s = 0.f;
    #pragma unroll
    for (int kp = 0; kp < KS; kp++) s += part[kp * stride + i];
    outp[i] = __float2bfloat16(tanhf(s));
}

// ---------------------------------------------------------------------------
// Split-K bf16 MFMA GEMM for token-mix LoRA1 ([4096,1024]@[1024,160]) with
// FUSED mix-input staging: A[row][k] = bf16(x + (x_prev - x)*x_maa[k]).
// ---------------------------------------------------------------------------
template <int KS>
__global__ __launch_bounds__(256) void gemm_mfma_sk(const float* __restrict__ x,
                                                    const float* __restrict__ x_maa,
                                                    const __hip_bfloat16* __restrict__ Bt,
                                                    float* __restrict__ part,
                                                    int M, int N, int K) {
    __shared__ alignas(16) unsigned short As[64 * 64];
    __shared__ alignas(16) unsigned short Bs[128 * 64];
    int tid = threadIdx.x;
    int m0 = blockIdx.y * 64, n0 = blockIdx.x * 128;
    int kp = blockIdx.z;
    int kbeg = kp * (K / KS), kend = kbeg + K / KS;
    int wave = tid >> 6, lane = tid & 63;
    int wm = (wave & 1) * 32, wn = (wave >> 1) * 64;
    int l15 = lane & 15, l4 = lane >> 4;
    f32x4_t acc[2][4] = {};

    for (int k0 = kbeg; k0 < kend; k0 += 64) {
        // A-staging with fused token-shift mix (reg-staged)
        #pragma unroll
        for (int p = 0; p < 2; p++) {
            int cch = tid + p * 256;
            int row = cch >> 3, slot = cch & 7;
            int s2 = slot ^ (row & 7);
            int gr = m0 + row;
            int t = gr & (Tn - 1);
            size_t gx = (size_t)gr * Cn + k0 + slot * 8;
            float4 xa0 = *reinterpret_cast<const float4*>(x + gx);
            float4 xa1 = *reinterpret_cast<const float4*>(x + gx + 4);
            float4 xp0 = make_float4(0.f, 0.f, 0.f, 0.f), xp1 = xp0;
            if (t > 0) {
                xp0 = *reinterpret_cast<const float4*>(x + gx - Cn);
                xp1 = *reinterpret_cast<const float4*>(x + gx - Cn + 4);
            }
            float4 ma0 = *reinterpret_cast<const float4*>(x_maa + k0 + slot * 8);
            float4 ma1 = *reinterpret_cast<const float4*>(x_maa + k0 + slot * 8 + 4);
            ushort4 o0, o1;
            o0.x = f2bf_bits(xa0.x + (xp0.x - xa0.x) * ma0.x);
            o0.y = f2bf_bits(xa0.y + (xp0.y - xa0.y) * ma0.y);
            o0.z = f2bf_bits(xa0.z + (xp0.z - xa0.z) * ma0.z);
            o0.w = f2bf_bits(xa0.w + (xp0.w - xa0.w) * ma0.w);
            o1.x = f2bf_bits(xa1.x + (xp1.x - xa1.x) * ma1.x);
            o1.y = f2bf_bits(xa1.y + (xp1.y - xa1.y) * ma1.y);
            o1.z = f2bf_bits(xa1.z + (xp1.z - xa1.z) * ma1.z);
            o1.w = f2bf_bits(xa1.w + (xp1.w - xa1.w) * ma1.w);
            *reinterpret_cast<ushort4*>(&As[row * 64 + s2 * 8]) = o0;
            *reinterpret_cast<ushort4*>(&As[row * 64 + s2 * 8 + 4]) = o1;
        }
        #pragma unroll
        for (int p = 0; p < 4; p++) {
            int cch = tid + p * 256;
            int row = cch >> 3, slot = cch & 7;
            int s2 = slot ^ (row & 7);
            int rowg = n0 + row; if (rowg > N - 1) rowg = N - 1;  // clamp
            *reinterpret_cast<us8_t*>(&Bs[row * 64 + s2 * 8]) =
                *reinterpret_cast<const us8_t*>(&Bt[(size_t)rowg * K + k0 + slot * 8]);
        }
        __syncthreads();
        #pragma unroll
        for (int kw = 0; kw < 2; kw++) {
            int slot = kw * 4 + l4;
            bf16x8_t af[2], bfr[4];
            #pragma unroll
            for (int f = 0; f < 2; f++) {
                int ar = wm + f * 16 + l15;
                af[f] = *reinterpret_cast<const bf16x8_t*>(&As[ar * 64 + (slot ^ (ar & 7)) * 8]);
            }
            #pragma unroll
            for (int f = 0; f < 4; f++) {
                int br = wn + f * 16 + l15;
                bfr[f] = *reinterpret_cast<const bf16x8_t*>(&Bs[br * 64 + (slot ^ (br & 7)) * 8]);
            }
            #pragma unroll
            for (int i = 0; i < 2; i++)
                #pragma unroll
                for (int j = 0; j < 4; j++)
                    acc[i][j] = __builtin_amdgcn_mfma_f32_16x16x32_bf16(af[i], bfr[j], acc[i][j], 0, 0, 0);
        }
        __syncthreads();
    }

    #pragma unroll
    for (int i = 0; i < 2; i++) {
        int rbase = m0 + wm + i * 16 + l4 * 4;
        #pragma unroll
        for (int j = 0; j < 4; j++) {
            int col = n0 + wn + j * 16 + l15;
            if (col < N) {
                #pragma unroll
                for (int q = 0; q < 4; q++)
                    part[((size_t)kp * M + rbase + q) * N + col] = acc[i][j][q];
            }
        }
    }
}

// ---------------------------------------------------------------------------
// Decay GEMM2 (bf16 MFMA, K=64 single tile): lwb = -exp(t_dec[col] +
//   wl1b[4096,64] @ tdw2T[1024,64]^T).  64x128 tile, m-fastest grid, f32 out.
// ---------------------------------------------------------------------------
__global__ __launch_bounds__(256) void gemm_mfma_decay(const __hip_bfloat16* __restrict__ A,
                                                       const __hip_bfloat16* __restrict__ Bt,
                                                       const float* __restrict__ extra,
                                                       float* __restrict__ Cout,
                                                       int M, int N) {
    __shared__ alignas(16) unsigned short As[64 * 64];
    __shared__ alignas(16) unsigned short Bs[128 * 64];
    int tid = threadIdx.x;
    int m0 = blockIdx.x * 64, n0 = blockIdx.y * 128;   // m fastest -> XCD=m%8
    int wave = tid >> 6, lane = tid & 63;
    int wm = (wave & 1) * 32, wn = (wave >> 1) * 64;
    int l15 = lane & 15, l4 = lane >> 4;
    int lrow = lane >> 3, ls2 = lane & 7;
    f32x4_t acc[2][4] = {};

    #pragma unroll
    for (int ci = 0; ci < 2; ci++) {
        int r0 = wave * 16 + ci * 8;
        int row = r0 + lrow;
        int gs = ls2 ^ (row & 7);
        gload16(&A[(size_t)(m0 + row) * 64 + gs * 8], &As[r0 * 64]);
    }
    #pragma unroll
    for (int ci = 0; ci < 4; ci++) {
        int r0 = wave * 32 + ci * 8;
        int row = r0 + lrow;
        int gs = ls2 ^ (row & 7);
        gload16(&Bt[(size_t)(n0 + row) * 64 + gs * 8], &Bs[r0 * 64]);
    }
    __syncthreads();
    #pragma unroll
    for (int kw = 0; kw < 2; kw++) {
        int slot = kw * 4 + l4;
        bf16x8_t af[2], bfr[4];
        #pragma unroll
        for (int f = 0; f < 2; f++) {
            int ar = wm + f * 16 + l15;
            af[f] = *reinterpret_cast<const bf16x8_t*>(&As[ar * 64 + (slot ^ (ar & 7)) * 8]);
        }
        #pragma unroll
        for (int f = 0; f < 4; f++) {
            int br = wn + f * 16 + l15;
            bfr[f] = *reinterpret_cast<const bf16x8_t*>(&Bs[br * 64 + (slot ^ (br & 7)) * 8]);
        }
        #pragma unroll
        for (int i = 0; i < 2; i++)
            #pragma unroll
            for (int j = 0; j < 4; j++)
                acc[i][j] = __builtin_amdgcn_mfma_f32_16x16x32_bf16(af[i], bfr[j], acc[i][j], 0, 0, 0);
    }

    #pragma unroll
    for (int i = 0; i < 2; i++) {
        int rbase = m0 + wm + i * 16 + l4 * 4;
        #pragma unroll
        for (int j = 0; j < 4; j++) {
            int col = n0 + wn + j * 16 + l15;
            float ex = extra[col];
            #pragma unroll
            for (int q = 0; q < 4; q++)
                Cout[(size_t)(rbase + q) * N + col] = -expf(ex + acc[i][j][q]);
        }
    }
}

// ---------------------------------------------------------------------------
// Deltas GEMM + FUSED token-shift mix (batched over f=blockIdx.z).
// ---------------------------------------------------------------------------
__global__ __launch_bounds__(256) void dmix_gemm(const __hip_bfloat16* __restrict__ A,
                                                 const __hip_bfloat16* __restrict__ W2T,
                                                 const float* __restrict__ x,
                                                 const float* __restrict__ wmaa,
                                                 const float* __restrict__ kmaa,
                                                 const float* __restrict__ vmaa,
                                                 const float* __restrict__ rmaa,
                                                 const float* __restrict__ gmaa,
                                                 float* __restrict__ wx,
                                                 __hip_bfloat16* __restrict__ kxb,
                                                 __hip_bfloat16* __restrict__ vxb,
                                                 __hip_bfloat16* __restrict__ rxb,
                                                 __hip_bfloat16* __restrict__ gxb) {
    __shared__ alignas(16) unsigned short As[64 * 32];
    __shared__ alignas(16) unsigned short Bs[128 * 32];
    int tid = threadIdx.x;
    int m0 = blockIdx.x * 64, n0 = blockIdx.y * 128;   // m fastest -> XCD=m%8
    int f  = blockIdx.z;
    int wave = tid >> 6, lane = tid & 63;
    int wm = (wave & 1) * 32, wn = (wave >> 1) * 64;
    int l15 = lane & 15, l4 = lane >> 4;
    int lrow2 = lane >> 2, ls = lane & 3;   // 16 rows x 4 slots per gload
    f32x4_t acc[2][4] = {};

    {
        int row = wave * 16 + lrow2;
        int gs = ls ^ (row & 3);
        gload16(&A[(size_t)(m0 + row) * 160 + f * 32 + gs * 8], &As[(wave * 16) * 32]);
    }
    #pragma unroll
    for (int ci = 0; ci < 2; ci++) {
        int r0 = wave * 32 + ci * 16;
        int row = r0 + lrow2;
        int gs = ls ^ (row & 3);
        gload16(&W2T[(size_t)(n0 + row) * 160 + f * 32 + gs * 8], &Bs[r0 * 32]);
    }
    __syncthreads();
    bf16x8_t af[2], bfr[4];
    #pragma unroll
    for (int i = 0; i < 2; i++) {
        int ar = wm + i * 16 + l15;
        af[i] = *reinterpret_cast<const bf16x8_t*>(&As[ar * 32 + ((l4 ^ (ar & 3)) * 8)]);
    }
    #pragma unroll
    for (int j = 0; j < 4; j++) {
        int br = wn + j * 16 + l15;
        bfr[j] = *reinterpret_cast<const bf16x8_t*>(&Bs[br * 32 + ((l4 ^ (br & 3)) * 8)]);
    }
    #pragma unroll
    for (int i = 0; i < 2; i++)
        #pragma unroll
        for (int j = 0; j < 4; j++)
            acc[i][j] = __builtin_amdgcn_mfma_f32_16x16x32_bf16(af[i], bfr[j], acc[i][j], 0, 0, 0);

    const float* maa = (f == 0) ? wmaa : (f == 1) ? kmaa : (f == 2) ? vmaa
                     : (f == 3) ? rmaa : gmaa;
    __hip_bfloat16* dstb = (f == 1) ? kxb : (f == 2) ? vxb : (f == 3) ? rxb : gxb;
    #pragma unroll
    for (int i = 0; i < 2; i++) {
        int rbase = m0 + wm + i * 16 + l4 * 4;
        #pragma unroll
        for (int j = 0; j < 4; j++) {
            int col = n0 + wn + j * 16 + l15;
            float mv = maa[col];
            #pragma unroll
            for (int q = 0; q < 4; q++) {
                int row = rbase + q;
                int t = row & (Tn - 1);
                size_t o = (size_t)row * Cn + col;
                float xv = x[o];
                float xp = (t > 0) ? x[o - Cn] : 0.f;
                float val = xv + (xp - xv) * (mv + acc[i][j][q]);
                if (f == 0) wx[o] = val;
                else        dstb[o] = __float2bfloat16(val);
            }
        }
    }
}

// ---------------------------------------------------------------------------
// GROUPED bf16 MFMA GEMM (16x16x32): 4 projections (r,k,v,g) in ONE dispatch.
// ---------------------------------------------------------------------------
__global__ __launch_bounds__(256) void gemm_qkvg(const __hip_bfloat16* __restrict__ A0,
                                                 const __hip_bfloat16* __restrict__ A1,
                                                 const __hip_bfloat16* __restrict__ A2,
                                                 const __hip_bfloat16* __restrict__ A3,
                                                 const __hip_bfloat16* __restrict__ B0,
                                                 const __hip_bfloat16* __restrict__ B1,
                                                 const __hip_bfloat16* __restrict__ B2,
                                                 const __hip_bfloat16* __restrict__ B3,
                                                 __hip_bfloat16* __restrict__ C0,
                                                 __hip_bfloat16* __restrict__ C1,
                                                 __hip_bfloat16* __restrict__ C2,
                                                 __hip_bfloat16* __restrict__ C3,
                                                 int M, int N, int K) {
    int g = blockIdx.z;
    const __hip_bfloat16* A  = (g == 0) ? A0 : (g == 1) ? A1 : (g == 2) ? A2 : A3;
    const __hip_bfloat16* Bt = (g == 0) ? B0 : (g == 1) ? B1 : (g == 2) ? B2 : B3;
    __hip_bfloat16* Co = (g == 0) ? C0 : (g == 1) ? C1 : (g == 2) ? C2 : C3;
    __shared__ alignas(16) unsigned short As[64 * 64];
    __shared__ alignas(16) unsigned short Bs[128 * 64];
    int tid = threadIdx.x;
    int m0 = blockIdx.x * 64, n0 = blockIdx.y * 128;   // m fastest -> XCD=m%8
    int wave = tid >> 6, lane = tid & 63;
    int wm = (wave & 1) * 32, wn = (wave >> 1) * 64;
    int l15 = lane & 15, l4 = lane >> 4;
    int lrow = lane >> 3, ls2 = lane & 7;
    f32x4_t acc[2][4] = {};

    for (int k0 = 0; k0 < K; k0 += 64) {
        #pragma unroll
        for (int ci = 0; ci < 2; ci++) {
            int r0 = wave * 16 + ci * 8;
            int row = r0 + lrow;
            int gs = ls2 ^ (row & 7);
            gload16(&A[(size_t)(m0 + row) * K + k0 + gs * 8], &As[r0 * 64]);
        }
        #pragma unroll
        for (int ci = 0; ci < 4; ci++) {
            int r0 = wave * 32 + ci * 8;
            int row = r0 + lrow;
            int gs = ls2 ^ (row & 7);
            gload16(&Bt[(size_t)(n0 + row) * K + k0 + gs * 8], &Bs[r0 * 64]);
        }
        __syncthreads();
        #pragma unroll
        for (int kw = 0; kw < 2; kw++) {
            int slot = kw * 4 + l4;
            bf16x8_t af[2], bfr[4];
            #pragma unroll
            for (int f = 0; f < 2; f++) {
                int ar = wm + f * 16 + l15;
                af[f] = *reinterpret_cast<const bf16x8_t*>(&As[ar * 64 + (slot ^ (ar & 7)) * 8]);
            }
            #pragma unroll
            for (int f = 0; f < 4; f++) {
                int br = wn + f * 16 + l15;
                bfr[f] = *reinterpret_cast<const bf16x8_t*>(&Bs[br * 64 + (slot ^ (br & 7)) * 8]);
            }
            #pragma unroll
            for (int i = 0; i < 2; i++)
                #pragma unroll
                for (int j = 0; j < 4; j++)
                    acc[i][j] = __builtin_amdgcn_mfma_f32_16x16x32_bf16(af[i], bfr[j], acc[i][j], 0, 0, 0);
        }
        __syncthreads();
    }

    #pragma unroll
    for (int i = 0; i < 2; i++) {
        int rbase = m0 + wm + i * 16 + l4 * 4;
        #pragma unroll
        for (int j = 0; j < 4; j++) {
            int col = n0 + wn + j * 16 + l15;
            #pragma unroll
            for (int q = 0; q < 4; q++) {
                float v = acc[i][j][q];
                if (g == 3) v = v / (1.f + expf(-v));
                Co[(size_t)(rbase + q) * N + col] = __float2bfloat16(v);
            }
        }
    }
}

// Wo projection (single, gl-staged, 64x128 tile, m-fastest grid), f32 out
__global__ __launch_bounds__(256) void gemm_mfma_gl(const __hip_bfloat16* __restrict__ A,
                                                    const __hip_bfloat16* __restrict__ Bt,
                                                    float* __restrict__ Cout,
                                                    int M, int N, int K) {
    __shared__ alignas(16) unsigned short As[64 * 64];
    __shared__ alignas(16) unsigned short Bs[128 * 64];
    int tid = threadIdx.x;
    int m0 = blockIdx.x * 64, n0 = blockIdx.y * 128;   // m fastest -> XCD=m%8
    int wave = tid >> 6, lane = tid & 63;
    int wm = (wave & 1) * 32, wn = (wave >> 1) * 64;
    int l15 = lane & 15, l4 = lane >> 4;
    int lrow = lane >> 3, ls2 = lane & 7;
    f32x4_t acc[2][4] = {};

    for (int k0 = 0; k0 < K; k0 += 64) {
        #pragma unroll
        for (int ci = 0; ci < 2; ci++) {
            int r0 = wave * 16 + ci * 8;
            int row = r0 + lrow;
            int gs = ls2 ^ (row & 7);
            gload16(&A[(size_t)(m0 + row) * K + k0 + gs * 8], &As[r0 * 64]);
        }
        #pragma unroll
        for (int ci = 0; ci < 4; ci++) {
            int r0 = wave * 32 + ci * 8;
            int row = r0 + lrow;
            int gs = ls2 ^ (row & 7);
            gload16(&Bt[(size_t)(n0 + row) * K + k0 + gs * 8], &Bs[r0 * 64]);
        }
        __syncthreads();
        #pragma unroll
        for (int kw = 0; kw < 2; kw++) {
            int slot = kw * 4 + l4;
            bf16x8_t af[2], bfr[4];
            #pragma unroll
            for (int f = 0; f < 2; f++) {
                int ar = wm + f * 16 + l15;
                af[f] = *reinterpret_cast<const bf16x8_t*>(&As[ar * 64 + (slot ^ (ar & 7)) * 8]);
            }
            #pragma unroll
            for (int f = 0; f < 4; f++) {
                int br = wn + f * 16 + l15;
                bfr[f] = *reinterpret_cast<const bf16x8_t*>(&Bs[br * 64 + (slot ^ (br & 7)) * 8]);
            }
            #pragma unroll
            for (int i = 0; i < 2; i++)
                #pragma unroll
                for (int j = 0; j < 4; j++)
                    acc[i][j] = __builtin_amdgcn_mfma_f32_16x16x32_bf16(af[i], bfr[j], acc[i][j], 0, 0, 0);
        }
        __syncthreads();
    }

    #pragma unroll
    for (int i = 0; i < 2; i++) {
        int rbase = m0 + wm + i * 16 + l4 * 4;
        #pragma unroll
        for (int j = 0; j < 4; j++) {
            int col = n0 + wn + j * 16 + l15;
            #pragma unroll
            for (int q = 0; q < 4; q++)
                Cout[(size_t)(rbase + q) * N + col] = acc[i][j][q];
        }
    }
}

// ---------------------------------------------------------------------------
// Chunked WKV stage A (MFMA): per (b,h,chunk). k/v inputs bf16; Bc out bf16.
// ---------------------------------------------------------------------------
__global__ __launch_bounds__(256) void chunk_summary(const __hip_bfloat16* __restrict__ kb,
                                                     const __hip_bfloat16* __restrict__ vb,
                                                     const float* __restrict__ lw,
                                                     __hip_bfloat16* __restrict__ Bc,
                                                     float* __restrict__ Wtot) {
    int bid = blockIdx.x;
    int c = bid & 15, h = (bid >> 4) & 15, b = bid >> 8;
    size_t gbase = ((size_t)(b * Tn + c * CL) * Hn + h) * 64;
    int tid = threadIdx.x;
    __shared__ float linc[64][68];
    __shared__ float wtp[4][64];
    __shared__ alignas(16) __hip_bfloat16 kdT[64][72];  // [ch][tau]
    __shared__ alignas(16) __hip_bfloat16 vsT[64][72];  // [v][tau]
    int wave = tid >> 6, lane = tid & 63;
    {
        float acc = 0.f;
        #pragma unroll
        for (int i = 0; i < 16; i++) {
            int t = wave * 16 + i;
            acc += lw[gbase + (size_t)t * 1024 + lane];
            linc[t][lane] = acc;
        }
        wtp[wave][lane] = acc;
    }
    __syncthreads();
    {
        float off = 0.f;
        for (int g = 0; g < wave; g++) off += wtp[g][lane];
        #pragma unroll
        for (int i = 0; i < 16; i++) linc[wave * 16 + i][lane] += off;
    }
    __syncthreads();
    int t4 = tid >> 2, c0 = (tid & 3) * 16;
    #pragma unroll
    for (int i = 0; i < 4; i++) {
        int ch = c0 + i * 4;
        size_t ga = gbase + (size_t)t4 * 1024 + ch;
        ushort4 ku = *reinterpret_cast<const ushort4*>(kb + ga);
        ushort4 vu = *reinterpret_cast<const ushort4*>(vb + ga);
        float kk[4] = {bfbits2f(ku.x), bfbits2f(ku.y), bfbits2f(ku.z), bfbits2f(ku.w)};
        float vv[4] = {bfbits2f(vu.x), bfbits2f(vu.y), bfbits2f(vu.z), bfbits2f(vu.w)};
        #pragma unroll
        for (int j = 0; j < 4; j++) {
            float li = linc[t4][ch + j];
            float lend = linc[63][ch + j];
            kdT[ch + j][t4] = __float2bfloat16(kk[j] * expf(lend - li));
            vsT[ch + j][t4] = __float2bfloat16(vv[j]);
        }
    }
    if (tid < 64) Wtot[(size_t)bid * 64 + tid] = expf(linc[63][tid]);
    __syncthreads();
    int l15 = lane & 15, l4q = lane >> 4;
    #pragma unroll
    for (int nt = 0; nt < 4; nt++) {
        f32x4_t acc = {};
        #pragma unroll
        for (int kt = 0; kt < 2; kt++) {
            bf16x8_t a = *reinterpret_cast<const bf16x8_t*>(&kdT[wave * 16 + l15][kt * 32 + l4q * 8]);
            bf16x8_t bb = *reinterpret_cast<const bf16x8_t*>(&vsT[nt * 16 + l15][kt * 32 + l4q * 8]);
            acc = __builtin_amdgcn_mfma_f32_16x16x32_bf16(a, bb, acc, 0, 0, 0);
        }
        #pragma unroll
        for (int q = 0; q < 4; q++) {
            int krow = wave * 16 + l4q * 4 + q;
            Bc[(size_t)bid * 4096 + (size_t)krow * 64 + nt * 16 + l15] = __float2bfloat16(acc[q]);
        }
    }
}

// ---------------------------------------------------------------------------
// Stage B: sequential scan over NC=16 chunk states (f32 accum internally);
// Bc in bf16, TRANSPOSED entry states out in bf16.
// ---------------------------------------------------------------------------
__global__ __launch_bounds__(256) void chunk_scan(const __hip_bfloat16* __restrict__ Bc,
                                                  const float* __restrict__ Wtot,
                                                  __hip_bfloat16* __restrict__ SbufT) {
    int bid = blockIdx.x;
    int bh = bid >> 2, vg = bid & 3;
    int kk = threadIdx.x >> 2;
    int v = vg * 16 + (threadIdx.x & 3) * 4;
    float4 S = make_float4(0.f, 0.f, 0.f, 0.f);
    for (int c = 0; c < NC; c++) {
        size_t base = (size_t)(bh * NC + c) * 4096;
        SbufT[base + (size_t)(v + 0) * 64 + kk] = __float2bfloat16(S.x);
        SbufT[base + (size_t)(v + 1) * 64 + kk] = __float2bfloat16(S.y);
        SbufT[base + (size_t)(v + 2) * 64 + kk] = __float2bfloat16(S.z);
        SbufT[base + (size_t)(v + 3) * 64 + kk] = __float2bfloat16(S.w);
        float wt = Wtot[(size_t)(bh * NC + c) * 64 + kk];
        ushort4 b4 = *reinterpret_cast<const ushort4*>(Bc + base + (size_t)kk * 64 + v);
        S.x = fmaf(wt, S.x, bfbits2f(b4.x));
        S.y = fmaf(wt, S.y, bfbits2f(b4.y));
        S.z = fmaf(wt, S.z, bfbits2f(b4.z));
        S.w = fmaf(wt, S.w, bfbits2f(b4.w));
    }
}

// ---------------------------------------------------------------------------
// Stage C (MFMA) + FUSED GroupNorm*g. SbufT input bf16.
// ---------------------------------------------------------------------------
__global__ __launch_bounds__(256) void chunk_out(const __hip_bfloat16* __restrict__ rb,
                                                 const __hip_bfloat16* __restrict__ kb,
                                                 const __hip_bfloat16* __restrict__ vb,
                                                 const float* __restrict__ lw,
                                                 const __hip_bfloat16* __restrict__ SbufT,
                                                 const float* __restrict__ tf,
                                                 const __hip_bfloat16* __restrict__ gb,
                                                 const float* __restrict__ lnw,
                                                 const float* __restrict__ lnb,
                                                 __hip_bfloat16* __restrict__ fin) {
    int bid = blockIdx.x;
    int c = bid & 15, h = (bid >> 4) & 15, b = bid >> 8;
    size_t gbase = ((size_t)(b * Tn + c * CL) * Hn + h) * 64;
    int tid = threadIdx.x;
    __shared__ alignas(16) __hip_bfloat16 qs[64][72];   // [t][ch]
    __shared__ alignas(16) __hip_bfloat16 ks[64][72];   // [tau][ch]
    __shared__ alignas(16) __hip_bfloat16 vsT[64][72];  // [v][tau]
    __shared__ alignas(16) __hip_bfloat16 scT[64][72];  // [v][ch]
    __shared__ alignas(16) float uni[64 * 68];          // linc, then asb
    __shared__ float wtp[4][64];
    __shared__ float diag[64];
    float (*linc)[68] = reinterpret_cast<float(*)[68]>(uni);
    __hip_bfloat16 (*asb)[72] = reinterpret_cast<__hip_bfloat16(*)[72]>(uni);
    int wave = tid >> 6, lane = tid & 63;
    {
        float acc = 0.f;
        #pragma unroll
        for (int i = 0; i < 16; i++) {
            int t = wave * 16 + i;
            acc += lw[gbase + (size_t)t * 1024 + lane];
            linc[t][lane] = acc;
        }
        wtp[wave][lane] = acc;
    }
    __syncthreads();
    {
        float off = 0.f;
        for (int g = 0; g < wave; g++) off += wtp[g][lane];
        #pragma unroll
        for (int i = 0; i < 16; i++) linc[wave * 16 + i][lane] += off;
    }
    __syncthreads();
    int t4 = tid >> 2, c0 = (tid & 3) * 16;
    float dpart = 0.f;
    #pragma unroll
    for (int i = 0; i < 4; i++) {
        int ch = c0 + i * 4;
        size_t ga = gbase + (size_t)t4 * 1024 + ch;
        ushort4 ru = *reinterpret_cast<const ushort4*>(rb + ga);
        ushort4 ku = *reinterpret_cast<const ushort4*>(kb + ga);
        ushort4 vu = *reinterpret_cast<const ushort4*>(vb + ga);
        float4 l4v = *reinterpret_cast<const float4*>(lw + ga);
        float4 u4 = *reinterpret_cast<const float4*>(tf + h * 64 + ch);
        ushort4 s4 = *reinterpret_cast<const ushort4*>(SbufT + (size_t)bid * 4096 + (size_t)t4 * 64 + ch);
        float rr[4] = {bfbits2f(ru.x), bfbits2f(ru.y), bfbits2f(ru.z), bfbits2f(ru.w)};
        float kkv[4] = {bfbits2f(ku.x), bfbits2f(ku.y), bfbits2f(ku.z), bfbits2f(ku.w)};
        float vv[4] = {bfbits2f(vu.x), bfbits2f(vu.y), bfbits2f(vu.z), bfbits2f(vu.w)};
        float lwv[4] = {l4v.x, l4v.y, l4v.z, l4v.w};
        float uu[4] = {u4.x, u4.y, u4.z, u4.w};
        unsigned short ssb[4] = {s4.x, s4.y, s4.z, s4.w};
        #pragma unroll
        for (int j = 0; j < 4; j++) {
            float li = linc[t4][ch + j];
            qs[t4][ch + j] = __float2bfloat16(rr[j] * expf(li - lwv[j]));
            ks[t4][ch + j] = __float2bfloat16(kkv[j] * expf(-li));
            vsT[ch + j][t4] = __float2bfloat16(vv[j]);
            *reinterpret_cast<unsigned short*>(&scT[t4][ch + j]) = ssb[j];   // row t4 = v
            dpart = fmaf(rr[j] * uu[j], kkv[j], dpart);
        }
    }
    dpart += __shfl_xor(dpart, 1);
    dpart += __shfl_xor(dpart, 2);
    if ((tid & 3) == 0) diag[t4] = dpart;
    __syncthreads();        // linc dead; asb may now overwrite uni
    int l15 = lane & 15, l4q = lane >> 4;
    #pragma unroll
    for (int nt = 0; nt < 4; nt++) {
        f32x4_t acc = {};
        if (nt <= wave) {
            #pragma unroll
            for (int kt = 0; kt < 2; kt++) {
                bf16x8_t a = *reinterpret_cast<const bf16x8_t*>(&qs[wave * 16 + l15][kt * 32 + l4q * 8]);
                bf16x8_t bb = *reinterpret_cast<const bf16x8_t*>(&ks[nt * 16 + l15][kt * 32 + l4q * 8]);
                acc = __builtin_amdgcn_mfma_f32_16x16x32_bf16(a, bb, acc, 0, 0, 0);
            }
        }
        #pragma unroll
        for (int q = 0; q < 4; q++) {
            int t = wave * 16 + l4q * 4 + q;
            int tau = nt * 16 + l15;
            float v = (tau < t) ? acc[q] : (tau == t ? diag[t] : 0.f);
            asb[t][tau] = __float2bfloat16(v);
        }
    }
    __syncthreads();
    // PV + state matmuls -> keep in regs for fused GN
    f32x4_t oacc[4];
    #pragma unroll
    for (int nt = 0; nt < 4; nt++) {
        f32x4_t acc = {};
        int kmax = (wave >> 1) + 1;
        for (int kt = 0; kt < kmax; kt++) {
            bf16x8_t a = *reinterpret_cast<const bf16x8_t*>(&asb[wave * 16 + l15][kt * 32 + l4q * 8]);
            bf16x8_t bb = *reinterpret_cast<const bf16x8_t*>(&vsT[nt * 16 + l15][kt * 32 + l4q * 8]);
            acc = __builtin_amdgcn_mfma_f32_16x16x32_bf16(a, bb, acc, 0, 0, 0);
        }
        #pragma unroll
        for (int kt = 0; kt < 2; kt++) {
            bf16x8_t a = *reinterpret_cast<const bf16x8_t*>(&qs[wave * 16 + l15][kt * 32 + l4q * 8]);
            bf16x8_t bb = *reinterpret_cast<const bf16x8_t*>(&scT[nt * 16 + l15][kt * 32 + l4q * 8]);
            acc = __builtin_amdgcn_mfma_f32_16x16x32_bf16(a, bb, acc, 0, 0, 0);
        }
        oacc[nt] = acc;
    }
    // Fused GroupNorm: row t = wave*16 + l4q*4 + q; 64 v spread over 16 lanes
    float sum[4] = {0.f, 0.f, 0.f, 0.f}, sq[4] = {0.f, 0.f, 0.f, 0.f};
    #pragma unroll
    for (int nt = 0; nt < 4; nt++)
        #pragma unroll
        for (int q = 0; q < 4; q++) {
            float v = oacc[nt][q] * 0.125f;   // / head_size_divisor
            oacc[nt][q] = v;
            sum[q] += v;
            sq[q] += v * v;
        }
    #pragma unroll
    for (int off = 1; off < 16; off <<= 1)
        #pragma unroll
        for (int q = 0; q < 4; q++) {
            sum[q] += __shfl_xor(sum[q], off, 64);
            sq[q]  += __shfl_xor(sq[q],  off, 64);
        }
    float mu[4], rs[4];
    #pragma unroll
    for (int q = 0; q < 4; q++) {
        mu[q] = sum[q] * (1.f / 64.f);
        float var = sq[q] * (1.f / 64.f) - mu[q] * mu[q];
        rs[q] = rsqrtf(var + 1e-5f);
    }
    #pragma unroll
    for (int nt = 0; nt < 4; nt++) {
        int v = nt * 16 + l15;
        float lw_ = lnw[h * 64 + v];
        float lb_ = lnb[h * 64 + v];
        #pragma unroll
        for (int q = 0; q < 4; q++) {
            int t = wave * 16 + l4q * 4 + q;
            size_t o = gbase + (size_t)t * 1024 + v;
            float gv = bfbits2f(*reinterpret_cast<const unsigned short*>(&gb[o]));
            float val = (oacc[nt][q] - mu[q]) * rs[q] * lw_ + lb_;
            fin[o] = __float2bfloat16(val * gv);
        }
    }
}

// ---------------------------------------------------------------------------
extern "C" void kernel_launch(void* const* d_in, const int* in_sizes, int n_in,
                              void* d_out, int out_size, void* d_ws, size_t ws_size,
                              hipStream_t stream) {
    (void)in_sizes; (void)n_in; (void)out_size; (void)ws_size;
    const float* x      = (const float*)d_in[0];
    const float* x_maa  = (const float*)d_in[1];
    const float* w_maa  = (const float*)d_in[2];
    const float* k_maa  = (const float*)d_in[3];
    const float* v_maa  = (const float*)d_in[4];
    const float* r_maa  = (const float*)d_in[5];
    const float* g_maa  = (const float*)d_in[6];
    const float* tm_w1  = (const float*)d_in[7];
    const float* tm_w2  = (const float*)d_in[8];
    const float* td_w1  = (const float*)d_in[9];
    const float* td_w2  = (const float*)d_in[10];
    const float* t_dec  = (const float*)d_in[11];
    const float* t_first= (const float*)d_in[12];
    const float* Wr     = (const float*)d_in[13];
    const float* Wk     = (const float*)d_in[14];
    const float* Wv     = (const float*)d_in[15];
    const float* Wg     = (const float*)d_in[16];
    const float* Wo     = (const float*)d_in[17];
    const float* ln_w   = (const float*)d_in[18];
    const float* ln_b   = (const float*)d_in[19];
    float* out = (float*)d_out;

    // Byte allocator, 256B aligned
    char* ws = (char*)d_ws;
    size_t off = 0;
    auto alloc = [&](size_t bytes) -> void* {
        void* p = ws + off;
        off = (off + bytes + 255) & ~(size_t)255;
        return p;
    };
    __hip_bfloat16* rb = (__hip_bfloat16*)alloc(BTC * 2);       // r projection
    __hip_bfloat16* mix160b = (__hip_bfloat16*)alloc((size_t)BT * 160 * 2);
    float* wxr    = (float*)alloc(BTC * 4);            // wx -> BcB (bf16, 8MB)
    __hip_bfloat16* kxb = (__hip_bfloat16*)alloc(BTC * 2);  // alias: fin
    __hip_bfloat16* vxb = (__hip_bfloat16*)alloc(BTC * 2);
    __hip_bfloat16* rxb = (__hip_bfloat16*)alloc(BTC * 2);  // alias: SbufT (bf16, 8MB)
    __hip_bfloat16* gxb = (__hip_bfloat16*)alloc(BTC * 2);
    __hip_bfloat16* kb  = (__hip_bfloat16*)alloc(BTC * 2);
    __hip_bfloat16* vb  = (__hip_bfloat16*)alloc(BTC * 2);
    __hip_bfloat16* gb  = (__hip_bfloat16*)alloc(BTC * 2);
    float* wl1 = (float*)alloc((size_t)BT * 64 * 4);   // spare
    float* lwb = (float*)alloc(BTC * 4);
    __hip_bfloat16* WrT = (__hip_bfloat16*)alloc((size_t)Cn * Cn * 2);
    __hip_bfloat16* WkT = (__hip_bfloat16*)alloc((size_t)Cn * Cn * 2);
    __hip_bfloat16* WvT = (__hip_bfloat16*)alloc((size_t)Cn * Cn * 2);
    __hip_bfloat16* WgT = (__hip_bfloat16*)alloc((size_t)Cn * Cn * 2);
    __hip_bfloat16* WoT = (__hip_bfloat16*)alloc((size_t)Cn * Cn * 2);
    __hip_bfloat16* tmw1T = (__hip_bfloat16*)alloc((size_t)160 * Cn * 2);
    __hip_bfloat16* w2T   = (__hip_bfloat16*)alloc((size_t)Cn * 160 * 2);
    __hip_bfloat16* tdw2T = (__hip_bfloat16*)alloc((size_t)Cn * 64 * 2);
    __hip_bfloat16* wl1b  = (__hip_bfloat16*)alloc((size_t)BT * 64 * 2);
    float* WtB = (float*)alloc((size_t)Bn * Hn * NC * 64 * 4);  // chunk decay totals
    // Time-shared region: lorapart (10.5MB) -> skpart (8MB), disjoint lifetimes
    char* big = (char*)alloc((size_t)4 * BT * 160 * 4);
    float* lorapart = (float*)big;             // [4][BT*160] f32
    float* skpart = (float*)big;               // [8][BT*64] f32
    (void)wl1;
    // Aliases (stream-ordered; producers complete before reuse):
    __hip_bfloat16* BcB = (__hip_bfloat16*)wxr;   // chunk contributions (wx dead after splitk)
    __hip_bfloat16* SbufT = rxb;   // entry states (transposed, bf16; rxb dead after qkvg)
    __hip_bfloat16* fin = kxb;     // fused-GN output (kxb dead after projections)

    dim3 blk(256);
    // weight transpose+convert: ALL 8 weights in one dispatch
    transp8<<<dim3(32, 32, 8), blk, 0, stream>>>(Wr, Wk, Wv, Wg, Wo, tm_w1, tm_w2, td_w2,
                                                 WrT, WkT, WvT, WgT, WoT, tmw1T, w2T, tdw2T);
    // token-mix LoRA1 (bf16 MFMA split-K, FUSED mix staging; 512 blocks)
    gemm_mfma_sk<4><<<dim3(2, 64, 4), blk, 0, stream>>>(x, x_maa, tmw1T, lorapart, BT, 160, Cn);
    splitk_reduce_tanh_bf<4><<<dim3((BT * 160 + 255) / 256), blk, 0, stream>>>(
        lorapart, mix160b, BT * 160, (size_t)BT * 160);
    // deltas: batched MFMA GEMM with FUSED token-shift mix epilogue
    dmix_gemm<<<dim3(64, 8, 5), blk, 0, stream>>>(mix160b, w2T, x,
                                                  w_maa, k_maa, v_maa, r_maa, g_maa,
                                                  wxr, kxb, vxb, rxb, gxb);
    // projections: ONE grouped dispatch (r,k,v,g), 16x16x32 MFMA, m-fastest grid
    gemm_qkvg<<<dim3(64, 8, 4), blk, 0, stream>>>(rxb, kxb, vxb, gxb,
                                                  WrT, WkT, WvT, WgT,
                                                  rb, kb, vb, gb, BT, Cn, Cn);
    // decay LoRA1 (f32 split-K, 512 blocks) + fused reduce/tanh -> bf16
    gemm_f32_splitk<8><<<dim3(8, 64), blk, 0, stream>>>(wxr, td_w1, skpart, BT, 64, Cn);
    splitk_reduce_tanh_bf<8><<<dim3(BT * 64 / 256), blk, 0, stream>>>(skpart, wl1b, BT * 64,
                                                                      (size_t)BT * 64);
    // decay GEMM2 (bf16 MFMA, K=64, log-decay epilogue, f32 out)
    gemm_mfma_decay<<<dim3(64, 8), blk, 0, stream>>>(wl1b, tdw2T, t_dec, lwb, BT, Cn);
    // chunked scan (MFMA); bf16 Bc/SbufT; chunk_out fuses GroupNorm*g
    chunk_summary<<<dim3(Bn * Hn * NC), blk, 0, stream>>>(kb, vb, lwb, BcB, WtB);
    chunk_scan<<<dim3(Bn * Hn * 4), blk, 0, stream>>>(BcB, WtB, SbufT);
    chunk_out<<<dim3(Bn * Hn * NC), blk, 0, stream>>>(rb, kb, vb, lwb, SbufT, t_first,
                                                      gb, ln_w, ln_b, fin);
    // output projection
    gemm_mfma_gl<<<dim3(64, 8), blk, 0, stream>>>(fin, WoT, out, BT, Cn, Cn);
}